// Round 1
// baseline (859.144 us; speedup 1.0000x reference)
//
#include <hip/hip_runtime.h>
#include <stdint.h>

typedef __bf16 bf16x8 __attribute__((ext_vector_type(8)));
typedef float f32x4 __attribute__((ext_vector_type(4)));

__device__ __forceinline__ float bf2f(unsigned short u) {
    return __uint_as_float(((unsigned)u) << 16);
}
__device__ __forceinline__ unsigned short f2bf(float f) {
    unsigned u = __float_as_uint(f);
    unsigned r = u + 0x7fffu + ((u >> 16) & 1u);  // RNE
    return (unsigned short)(r >> 16);
}
__device__ __forceinline__ void unpack4(uint2 u, float& a, float& b, float& c, float& d) {
    a = __uint_as_float(u.x << 16);
    b = __uint_as_float(u.x & 0xffff0000u);
    c = __uint_as_float(u.y << 16);
    d = __uint_as_float(u.y & 0xffff0000u);
}
__device__ __forceinline__ uint2 pack4(float a, float b, float c, float d) {
    uint2 o;
    o.x = (unsigned)f2bf(a) | ((unsigned)f2bf(b) << 16);
    o.y = (unsigned)f2bf(c) | ((unsigned)f2bf(d) << 16);
    return o;
}

// ---------------- conversion / transpose ----------------

__global__ void cvt_x_kernel(const float* __restrict__ x, unsigned short* __restrict__ xbf, int n) {
    int i = (blockIdx.x * 256 + threadIdx.x) * 4;
    if (i < n) {
        float4 v = *reinterpret_cast<const float4*>(x + i);
        *reinterpret_cast<uint2*>(xbf + i) = pack4(v.x, v.y, v.z, v.w);
    }
}

__global__ void tr_node_kernel(const float* __restrict__ w, unsigned short* __restrict__ wT) {
    int idx = blockIdx.x * 256 + threadIdx.x;  // over 64*256
    if (idx < 64 * 256) {
        int k = idx >> 8, n = idx & 255;
        wT[n * 64 + k] = f2bf(w[idx]);
    }
}

__global__ void tr_conv_kernel(const float* __restrict__ w, unsigned short* __restrict__ wT) {
    int idx = blockIdx.x * 256 + threadIdx.x;  // over 3*256*256
    if (idx < 3 * 256 * 256) {
        int l = idx >> 16, rem = idx & 65535;
        int k = rem >> 8, n = rem & 255;
        wT[(l << 16) + (n << 8) + k] = f2bf(w[idx]);
    }
}

// ---------------- degree / CSR build ----------------

__global__ void deg_kernel(const int* __restrict__ col, int* __restrict__ cnt, int E) {
    int e = blockIdx.x * 256 + threadIdx.x;
    if (e < E) atomicAdd(&cnt[col[e]], 1);
}

__global__ void dis_kernel(const int* __restrict__ cnt, float* __restrict__ dis, int N) {
    int v = blockIdx.x * 256 + threadIdx.x;
    if (v < N) dis[v] = rsqrtf((float)cnt[v] + 1.0f);  // +1 self-loop
}

__global__ void scan1_kernel(const int* __restrict__ cnt, int* __restrict__ scanbuf,
                             int* __restrict__ bsum, int N) {
    __shared__ int s[512];
    int i = blockIdx.x * 512 + threadIdx.x;
    s[threadIdx.x] = (i < N) ? cnt[i] : 0;
    __syncthreads();
    for (int off = 1; off < 512; off <<= 1) {
        int t = (threadIdx.x >= off) ? s[threadIdx.x - off] : 0;
        __syncthreads();
        s[threadIdx.x] += t;
        __syncthreads();
    }
    if (i < N) scanbuf[i] = s[threadIdx.x];
    if (threadIdx.x == 511) bsum[blockIdx.x] = s[511];
}

__global__ void scan2_kernel(const int* __restrict__ bsum, int* __restrict__ boff, int nb) {
    if (threadIdx.x == 0 && blockIdx.x == 0) {
        int acc = 0;
        for (int b = 0; b < nb; b++) { boff[b] = acc; acc += bsum[b]; }
    }
}

__global__ void scan3_kernel(const int* __restrict__ scanbuf, const int* __restrict__ boff,
                             int* __restrict__ rowstart, int N) {
    int i = blockIdx.x * 256 + threadIdx.x;
    if (i < N) rowstart[i + 1] = scanbuf[i] + boff[i >> 9];
    if (i == 0) rowstart[0] = 0;
}

__global__ void scatter_kernel(const int* __restrict__ row, const int* __restrict__ col,
                               const int* __restrict__ rowstart, int* __restrict__ fill,
                               int* __restrict__ eidx, int E) {
    int e = blockIdx.x * 256 + threadIdx.x;
    if (e < E) {
        int c = col[e];
        int pos = rowstart[c] + atomicAdd(&fill[c], 1);
        eidx[pos] = row[e];
    }
}

// ---------------- GEMM: C[M,Nc] = A[M,K] * B[K,Nc], B given transposed (BT[Nc,K]) ----------------
// bf16 inputs, fp32 MFMA accumulate, bf16 out (+ optional fp32 bias).
// Block 256 thr = 4 waves (2x2), block tile 128x128, wave tile 64x64 (4x4 of 16x16x32 MFMA).

__global__ __launch_bounds__(256)
void gemm_bt_kernel(const unsigned short* __restrict__ A, const unsigned short* __restrict__ BT,
                    unsigned short* __restrict__ C, const float* __restrict__ bias,
                    int M, int K, int Nc) {
    const int lane = threadIdx.x & 63;
    const int wave = threadIdx.x >> 6;
    const int wm = wave >> 1, wn = wave & 1;
    const int r = lane & 15, q = lane >> 4;
    const int m0 = blockIdx.x * 128 + wm * 64;
    const int n0 = blockIdx.y * 128 + wn * 64;

    f32x4 acc[4][4] = {};

    for (int k0 = 0; k0 < K; k0 += 32) {
        bf16x8 a[4], b[4];
#pragma unroll
        for (int i = 0; i < 4; i++) {
            int mr = m0 + i * 16 + r;
            if (mr >= M) mr = M - 1;  // clamp; masked at store
            a[i] = *reinterpret_cast<const bf16x8*>(A + (size_t)mr * K + k0 + q * 8);
        }
#pragma unroll
        for (int j = 0; j < 4; j++) {
            int nr = n0 + j * 16 + r;
            b[j] = *reinterpret_cast<const bf16x8*>(BT + (size_t)nr * K + k0 + q * 8);
        }
#pragma unroll
        for (int i = 0; i < 4; i++)
#pragma unroll
            for (int j = 0; j < 4; j++)
                acc[i][j] = __builtin_amdgcn_mfma_f32_16x16x32_bf16(a[i], b[j], acc[i][j], 0, 0, 0);
    }

#pragma unroll
    for (int i = 0; i < 4; i++) {
#pragma unroll
        for (int t = 0; t < 4; t++) {
            int mr = m0 + i * 16 + q * 4 + t;  // C/D: row = q*4+reg, col = lane&15
            if (mr < M) {
#pragma unroll
                for (int j = 0; j < 4; j++) {
                    int nc = n0 + j * 16 + r;
                    float v = acc[i][j][t];
                    if (bias) v += bias[nc];
                    C[(size_t)mr * Nc + nc] = f2bf(v);
                }
            }
        }
    }
}

// ---------------- aggregation (GCN message passing) + fused BN stats ----------------
// agg[v] = conv_b + dis[v]^2 * hw[v] + sum_{e: col=v} dis[src]*dis[v] * hw[src]
// Block 256 thr = 4 waves; each wave handles 4 nodes; lane owns 4 features.

__global__ __launch_bounds__(256)
void agg_kernel(const unsigned short* __restrict__ hw, const int* __restrict__ rowstart,
                const int* __restrict__ eidx, const float* __restrict__ dis,
                const float* __restrict__ cb, float* __restrict__ agg,
                float* __restrict__ stats, int N) {
    __shared__ float s_sum[4][256];
    __shared__ float s_sq[4][256];
    const int lane = threadIdx.x & 63;
    const int wave = threadIdx.x >> 6;
    const int f0 = lane * 4;

    const float c0 = cb[f0], c1 = cb[f0 + 1], c2 = cb[f0 + 2], c3 = cb[f0 + 3];
    float ps0 = 0, ps1 = 0, ps2 = 0, ps3 = 0;
    float pq0 = 0, pq1 = 0, pq2 = 0, pq3 = 0;

#pragma unroll
    for (int s = 0; s < 4; s++) {
        int v = blockIdx.x * 16 + wave * 4 + s;
        if (v < N) {
            float dv = dis[v];
            float x0, x1, x2, x3;
            uint2 raw = *reinterpret_cast<const uint2*>(hw + (size_t)v * 256 + f0);
            unpack4(raw, x0, x1, x2, x3);
            float dv2 = dv * dv;
            float a0 = c0 + dv2 * x0, a1 = c1 + dv2 * x1;
            float a2 = c2 + dv2 * x2, a3 = c3 + dv2 * x3;
            int js = rowstart[v], je = rowstart[v + 1];
            for (int j = js; j < je; j++) {
                int src = eidx[j];
                float wgt = dis[src] * dv;
                uint2 rw = *reinterpret_cast<const uint2*>(hw + (size_t)src * 256 + f0);
                unpack4(rw, x0, x1, x2, x3);
                a0 += wgt * x0; a1 += wgt * x1; a2 += wgt * x2; a3 += wgt * x3;
            }
            *reinterpret_cast<float4*>(agg + (size_t)v * 256 + f0) = make_float4(a0, a1, a2, a3);
            ps0 += a0; ps1 += a1; ps2 += a2; ps3 += a3;
            pq0 += a0 * a0; pq1 += a1 * a1; pq2 += a2 * a2; pq3 += a3 * a3;
        }
    }

    s_sum[wave][f0] = ps0; s_sum[wave][f0 + 1] = ps1;
    s_sum[wave][f0 + 2] = ps2; s_sum[wave][f0 + 3] = ps3;
    s_sq[wave][f0] = pq0; s_sq[wave][f0 + 1] = pq1;
    s_sq[wave][f0 + 2] = pq2; s_sq[wave][f0 + 3] = pq3;
    __syncthreads();

    int f = threadIdx.x;
    float ts = s_sum[0][f] + s_sum[1][f] + s_sum[2][f] + s_sum[3][f];
    float tq = s_sq[0][f] + s_sq[1][f] + s_sq[2][f] + s_sq[3][f];
    atomicAdd(&stats[f], ts);
    atomicAdd(&stats[256 + f], tq);
}

__global__ void bnfin_kernel(const float* __restrict__ stats, const float* __restrict__ g,
                             const float* __restrict__ b, float* __restrict__ ss, int N) {
    int f = threadIdx.x;
    float inv_n = 1.0f / (float)N;
    float mean = stats[f] * inv_n;
    float var = stats[256 + f] * inv_n - mean * mean;
    float rstd = rsqrtf(var + 1e-5f);
    float sc = g[f] * rstd;
    ss[f] = sc;
    ss[256 + f] = b[f] - mean * sc;
}

__global__ void elem_kernel(const float* __restrict__ agg, const float* __restrict__ ss,
                            unsigned short* __restrict__ h, size_t total) {
    size_t i = ((size_t)blockIdx.x * 256 + threadIdx.x) * 4;
    if (i < total) {
        float4 a = *reinterpret_cast<const float4*>(agg + i);
        int f = (int)(i & 255);
        float r0 = fmaxf(a.x * ss[f] + ss[256 + f], 0.0f);
        float r1 = fmaxf(a.y * ss[f + 1] + ss[256 + f + 1], 0.0f);
        float r2 = fmaxf(a.z * ss[f + 2] + ss[256 + f + 2], 0.0f);
        float r3 = fmaxf(a.w * ss[f + 3] + ss[256 + f + 3], 0.0f);
        *reinterpret_cast<uint2*>(h + i) = pack4(r0, r1, r2, r3);
    }
}

// ---------------- global_add_pool (batch is sorted) ----------------

__global__ __launch_bounds__(256)
void pool_kernel(const unsigned short* __restrict__ h, const int* __restrict__ batch,
                 float* __restrict__ g, int N) {
    __shared__ int sb[256];
    int f = threadIdx.x;
    int r0 = blockIdx.x * 256;
    int rows = min(256, N - r0);
    sb[f] = (r0 + f < N) ? batch[r0 + f] : -1;
    __syncthreads();
    float acc = 0.0f;
    int cur = sb[0];
    for (int t = 0; t < rows; t++) {
        int b = sb[t];
        if (b != cur) {
            atomicAdd(&g[cur * 256 + f], acc);
            acc = 0.0f;
            cur = b;
        }
        acc += bf2f(h[(size_t)(r0 + t) * 256 + f]);
    }
    atomicAdd(&g[cur * 256 + f], acc);
}

// ---------------- head MLP: relu(g@w1+b1)@w2+b2 ----------------

__global__ void head_kernel(const float* __restrict__ g, const float* __restrict__ w1,
                            const float* __restrict__ b1, const float* __restrict__ w2,
                            const float* __restrict__ b2, float* __restrict__ out) {
    __shared__ float gr[256];
    __shared__ float z[128];
    int b = blockIdx.x, t = threadIdx.x;
    gr[t] = g[b * 256 + t];
    gr[t + 128] = g[b * 256 + 128 + t];
    __syncthreads();
    float acc = b1[t];
    for (int k = 0; k < 256; k++) acc += gr[k] * w1[k * 128 + t];
    z[t] = fmaxf(acc, 0.0f);
    __syncthreads();
    if (t < 12) {
        float o = b2[t];
        for (int k = 0; k < 128; k++) o += z[k] * w2[k * 12 + t];
        out[b * 12 + t] = o;
    }
}

// ---------------- launch ----------------

extern "C" void kernel_launch(void* const* d_in, const int* in_sizes, int n_in,
                              void* d_out, int out_size, void* d_ws, size_t ws_size,
                              hipStream_t stream) {
    const float* x      = (const float*)d_in[0];
    const int*   ei     = (const int*)d_in[1];
    const int*   batch  = (const int*)d_in[2];
    const float* node_w = (const float*)d_in[3];
    const float* node_b = (const float*)d_in[4];
    const float* conv_w = (const float*)d_in[5];
    const float* conv_b = (const float*)d_in[6];
    const float* bn_g   = (const float*)d_in[7];
    const float* bn_b   = (const float*)d_in[8];
    const float* hw1    = (const float*)d_in[9];
    const float* hb1    = (const float*)d_in[10];
    const float* hw2    = (const float*)d_in[11];
    const float* hb2    = (const float*)d_in[12];
    float* out = (float*)d_out;

    const int N = in_sizes[2];
    const int E = in_sizes[1] / 2;
    const int IN = 64, H = 256, L = 3;

    char* base = (char*)d_ws;
    size_t off = 0;
    auto alloc = [&](size_t bytes) -> void* {
        off = (off + 255) & ~(size_t)255;
        void* p = base + off;
        off += bytes;
        return p;
    };
    unsigned short* xbf = (unsigned short*)alloc((size_t)N * IN * 2);
    unsigned short* h   = (unsigned short*)alloc((size_t)N * H * 2);
    unsigned short* hw  = (unsigned short*)alloc((size_t)N * H * 2);
    float* agg          = (float*)alloc((size_t)N * H * 4);
    unsigned short* nwT = (unsigned short*)alloc((size_t)IN * H * 2);
    unsigned short* cwT = (unsigned short*)alloc((size_t)L * H * H * 2);
    int* cnt      = (int*)alloc((size_t)N * 4);
    int* fill     = (int*)alloc((size_t)N * 4);
    int* rowstart = (int*)alloc((size_t)(N + 1) * 4);
    int* scanbuf  = (int*)alloc((size_t)N * 4);
    int* bsum     = (int*)alloc(1024);
    int* boff     = (int*)alloc(1024);
    int* eidx     = (int*)alloc((size_t)E * 4);
    float* dis    = (float*)alloc((size_t)N * 4);
    float* stats  = (float*)alloc(512 * 4);
    float* ss     = (float*)alloc(512 * 4);
    float* gpool  = (float*)alloc(64 * H * 4);

    const int* row = ei;
    const int* col = ei + E;

    hipMemsetAsync(cnt, 0, (size_t)N * 4, stream);
    hipMemsetAsync(fill, 0, (size_t)N * 4, stream);

    cvt_x_kernel<<<dim3((N * IN / 4 + 255) / 256), 256, 0, stream>>>(x, xbf, N * IN);
    tr_node_kernel<<<dim3((IN * H + 255) / 256), 256, 0, stream>>>(node_w, nwT);
    tr_conv_kernel<<<dim3((L * H * H + 255) / 256), 256, 0, stream>>>(conv_w, cwT);

    deg_kernel<<<dim3((E + 255) / 256), 256, 0, stream>>>(col, cnt, E);
    dis_kernel<<<dim3((N + 255) / 256), 256, 0, stream>>>(cnt, dis, N);
    int nb = (N + 511) / 512;
    scan1_kernel<<<dim3(nb), 512, 0, stream>>>(cnt, scanbuf, bsum, N);
    scan2_kernel<<<dim3(1), 64, 0, stream>>>(bsum, boff, nb);
    scan3_kernel<<<dim3((N + 255) / 256), 256, 0, stream>>>(scanbuf, boff, rowstart, N);
    scatter_kernel<<<dim3((E + 255) / 256), 256, 0, stream>>>(row, col, rowstart, fill, eidx, E);

    dim3 gg((N + 127) / 128, H / 128);
    gemm_bt_kernel<<<gg, 256, 0, stream>>>(xbf, nwT, h, node_b, N, IN, H);

    for (int l = 0; l < L; l++) {
        gemm_bt_kernel<<<gg, 256, 0, stream>>>(h, cwT + (size_t)l * H * H, hw, nullptr, N, H, H);
        hipMemsetAsync(stats, 0, 512 * 4, stream);
        agg_kernel<<<dim3((N + 15) / 16), 256, 0, stream>>>(hw, rowstart, eidx, dis,
                                                            conv_b + l * H, agg, stats, N);
        bnfin_kernel<<<dim3(1), 256, 0, stream>>>(stats, bn_g + l * H, bn_b + l * H, ss, N);
        size_t total = (size_t)N * H;
        elem_kernel<<<dim3((int)((total / 4 + 255) / 256)), 256, 0, stream>>>(agg, ss, h, total);
    }

    hipMemsetAsync(gpool, 0, 64 * H * 4, stream);
    pool_kernel<<<dim3((N + 255) / 256), 256, 0, stream>>>(h, batch, gpool, N);
    head_kernel<<<dim3(64), 128, 0, stream>>>(gpool, hw1, hb1, hw2, hb2, out);
}

// Round 2
// 744.081 us; speedup vs baseline: 1.1546x; 1.1546x over previous
//
#include <hip/hip_runtime.h>
#include <stdint.h>

typedef __bf16 bf16x8 __attribute__((ext_vector_type(8)));
typedef float f32x4 __attribute__((ext_vector_type(4)));

__device__ __forceinline__ float bf2f(unsigned short u) {
    return __uint_as_float(((unsigned)u) << 16);
}
__device__ __forceinline__ unsigned short f2bf(float f) {
    unsigned u = __float_as_uint(f);
    unsigned r = u + 0x7fffu + ((u >> 16) & 1u);  // RNE
    return (unsigned short)(r >> 16);
}
__device__ __forceinline__ void unpack4(uint2 u, float& a, float& b, float& c, float& d) {
    a = __uint_as_float(u.x << 16);
    b = __uint_as_float(u.x & 0xffff0000u);
    c = __uint_as_float(u.y << 16);
    d = __uint_as_float(u.y & 0xffff0000u);
}
__device__ __forceinline__ uint2 pack4(float a, float b, float c, float d) {
    uint2 o;
    o.x = (unsigned)f2bf(a) | ((unsigned)f2bf(b) << 16);
    o.y = (unsigned)f2bf(c) | ((unsigned)f2bf(d) << 16);
    return o;
}

// ---------------- conversion / transpose ----------------

__global__ void cvt_x_kernel(const float* __restrict__ x, unsigned short* __restrict__ xbf, int n) {
    int i = (blockIdx.x * 256 + threadIdx.x) * 4;
    if (i < n) {
        float4 v = *reinterpret_cast<const float4*>(x + i);
        *reinterpret_cast<uint2*>(xbf + i) = pack4(v.x, v.y, v.z, v.w);
    }
}

__global__ void tr_node_kernel(const float* __restrict__ w, unsigned short* __restrict__ wT) {
    int idx = blockIdx.x * 256 + threadIdx.x;  // over 64*256
    if (idx < 64 * 256) {
        int k = idx >> 8, n = idx & 255;
        wT[n * 64 + k] = f2bf(w[idx]);
    }
}

__global__ void tr_conv_kernel(const float* __restrict__ w, unsigned short* __restrict__ wT) {
    int idx = blockIdx.x * 256 + threadIdx.x;  // over 3*256*256
    if (idx < 3 * 256 * 256) {
        int l = idx >> 16, rem = idx & 65535;
        int k = rem >> 8, n = rem & 255;
        wT[(l << 16) + (n << 8) + k] = f2bf(w[idx]);
    }
}

// ---------------- degree / CSR build ----------------

__global__ void deg_kernel(const int* __restrict__ col, int* __restrict__ cnt, int E) {
    int e = blockIdx.x * 256 + threadIdx.x;
    if (e < E) atomicAdd(&cnt[col[e]], 1);
}

__global__ void dis_kernel(const int* __restrict__ cnt, float* __restrict__ dis, int N) {
    int v = blockIdx.x * 256 + threadIdx.x;
    if (v < N) dis[v] = rsqrtf((float)cnt[v] + 1.0f);  // +1 self-loop
}

__global__ void scan1_kernel(const int* __restrict__ cnt, int* __restrict__ scanbuf,
                             int* __restrict__ bsum, int N) {
    __shared__ int s[512];
    int i = blockIdx.x * 512 + threadIdx.x;
    s[threadIdx.x] = (i < N) ? cnt[i] : 0;
    __syncthreads();
    for (int off = 1; off < 512; off <<= 1) {
        int t = (threadIdx.x >= off) ? s[threadIdx.x - off] : 0;
        __syncthreads();
        s[threadIdx.x] += t;
        __syncthreads();
    }
    if (i < N) scanbuf[i] = s[threadIdx.x];
    if (threadIdx.x == 511) bsum[blockIdx.x] = s[511];
}

__global__ void scan2_kernel(const int* __restrict__ bsum, int* __restrict__ boff, int nb) {
    if (threadIdx.x == 0 && blockIdx.x == 0) {
        int acc = 0;
        for (int b = 0; b < nb; b++) { boff[b] = acc; acc += bsum[b]; }
    }
}

__global__ void scan3_kernel(const int* __restrict__ scanbuf, const int* __restrict__ boff,
                             int* __restrict__ rowstart, int N) {
    int i = blockIdx.x * 256 + threadIdx.x;
    if (i < N) rowstart[i + 1] = scanbuf[i] + boff[i >> 9];
    if (i == 0) rowstart[0] = 0;
}

__global__ void scatter_kernel(const int* __restrict__ row, const int* __restrict__ col,
                               const int* __restrict__ rowstart, int* __restrict__ fill,
                               int* __restrict__ eidx, int E) {
    int e = blockIdx.x * 256 + threadIdx.x;
    if (e < E) {
        int c = col[e];
        int pos = rowstart[c] + atomicAdd(&fill[c], 1);
        eidx[pos] = row[e];
    }
}

__global__ void zrow_kernel(unsigned short* __restrict__ p) {
    p[threadIdx.x] = 0;  // 256-wide zero row
}

// ---------------- GEMM: C[M,Nc] = A[M,K] * B[K,Nc], B given transposed (BT[Nc,K]) ----------------
// bf16 inputs, fp32 MFMA accumulate, bf16 out. Optional fp32 bias[nc] and per-row scale[mr].
// Block 256 thr = 4 waves (2x2), block tile 128x128, wave tile 64x64 (4x4 of 16x16x32 MFMA).

__global__ __launch_bounds__(256)
void gemm_bt_kernel(const unsigned short* __restrict__ A, const unsigned short* __restrict__ BT,
                    unsigned short* __restrict__ C, const float* __restrict__ bias,
                    const float* __restrict__ scale, int M, int K, int Nc) {
    const int lane = threadIdx.x & 63;
    const int wave = threadIdx.x >> 6;
    const int wm = wave >> 1, wn = wave & 1;
    const int r = lane & 15, q = lane >> 4;
    const int m0 = blockIdx.x * 128 + wm * 64;
    const int n0 = blockIdx.y * 128 + wn * 64;

    f32x4 acc[4][4] = {};

    for (int k0 = 0; k0 < K; k0 += 32) {
        bf16x8 a[4], b[4];
#pragma unroll
        for (int i = 0; i < 4; i++) {
            int mr = m0 + i * 16 + r;
            if (mr >= M) mr = M - 1;  // clamp; masked at store
            a[i] = *reinterpret_cast<const bf16x8*>(A + (size_t)mr * K + k0 + q * 8);
        }
#pragma unroll
        for (int j = 0; j < 4; j++) {
            int nr = n0 + j * 16 + r;
            b[j] = *reinterpret_cast<const bf16x8*>(BT + (size_t)nr * K + k0 + q * 8);
        }
#pragma unroll
        for (int i = 0; i < 4; i++)
#pragma unroll
            for (int j = 0; j < 4; j++)
                acc[i][j] = __builtin_amdgcn_mfma_f32_16x16x32_bf16(a[i], b[j], acc[i][j], 0, 0, 0);
    }

#pragma unroll
    for (int i = 0; i < 4; i++) {
#pragma unroll
        for (int t = 0; t < 4; t++) {
            int mr = m0 + i * 16 + q * 4 + t;  // C/D: row = q*4+reg, col = lane&15
            if (mr < M) {
                float rs = scale ? scale[mr] : 1.0f;
#pragma unroll
                for (int j = 0; j < 4; j++) {
                    int nc = n0 + j * 16 + r;
                    float v = acc[i][j][t] * rs;
                    if (bias) v += bias[nc];
                    C[(size_t)mr * Nc + nc] = f2bf(v);
                }
            }
        }
    }
}

// ---------------- aggregation (GCN message passing) + fused BN stats ----------------
// hws[v] = dis[v] * (h @ W)[v]  (pre-scaled in GEMM epilogue); hws[N] is a zero row.
// agg[v] = conv_b + dis[v] * ( hws[v] + sum_{e: col=v} hws[src] )
// Block 256 thr = 4 waves; each wave handles 4 nodes; lane owns 4 features.
// Neighbor loop: coalesced 64-index chunk + shfl broadcast, 4 row-loads in flight,
// ragged groups padded with the zero row (no tail code).

__global__ __launch_bounds__(256)
void agg_kernel(const unsigned short* __restrict__ hws, const int* __restrict__ rowstart,
                const int* __restrict__ eidx, const float* __restrict__ dis,
                const float* __restrict__ cb, unsigned short* __restrict__ agg,
                float* __restrict__ stats, int N) {
    __shared__ float s_sum[4][256];
    __shared__ float s_sq[4][256];
    const int lane = threadIdx.x & 63;
    const int wave = threadIdx.x >> 6;
    const int f0 = lane * 4;

    const float c0 = cb[f0], c1 = cb[f0 + 1], c2 = cb[f0 + 2], c3 = cb[f0 + 3];
    float ps0 = 0, ps1 = 0, ps2 = 0, ps3 = 0;
    float pq0 = 0, pq1 = 0, pq2 = 0, pq3 = 0;

#pragma unroll
    for (int s = 0; s < 4; s++) {
        int v = blockIdx.x * 16 + wave * 4 + s;
        if (v < N) {
            float dv = dis[v];
            float x0, x1, x2, x3;
            uint2 raw = *reinterpret_cast<const uint2*>(hws + (size_t)v * 256 + f0);
            unpack4(raw, x0, x1, x2, x3);
            float a0 = x0, a1 = x1, a2 = x2, a3 = x3;

            int js = rowstart[v], je = rowstart[v + 1];
            int deg = je - js;
            for (int base = 0; base < deg; base += 64) {
                int cn = min(64, deg - base);
                int myidx = (lane < cn) ? eidx[js + base + lane] : N;  // N -> zero row
                for (int t = 0; t < cn; t += 4) {
                    int u0 = __shfl(myidx, t);
                    int u1 = __shfl(myidx, t + 1);
                    int u2 = __shfl(myidx, t + 2);
                    int u3 = __shfl(myidx, t + 3);
                    uint2 r0 = *reinterpret_cast<const uint2*>(hws + (size_t)u0 * 256 + f0);
                    uint2 r1 = *reinterpret_cast<const uint2*>(hws + (size_t)u1 * 256 + f0);
                    uint2 r2 = *reinterpret_cast<const uint2*>(hws + (size_t)u2 * 256 + f0);
                    uint2 r3 = *reinterpret_cast<const uint2*>(hws + (size_t)u3 * 256 + f0);
                    unpack4(r0, x0, x1, x2, x3);
                    a0 += x0; a1 += x1; a2 += x2; a3 += x3;
                    unpack4(r1, x0, x1, x2, x3);
                    a0 += x0; a1 += x1; a2 += x2; a3 += x3;
                    unpack4(r2, x0, x1, x2, x3);
                    a0 += x0; a1 += x1; a2 += x2; a3 += x3;
                    unpack4(r3, x0, x1, x2, x3);
                    a0 += x0; a1 += x1; a2 += x2; a3 += x3;
                }
            }

            float g0 = c0 + dv * a0, g1 = c1 + dv * a1;
            float g2 = c2 + dv * a2, g3 = c3 + dv * a3;
            *reinterpret_cast<uint2*>(agg + (size_t)v * 256 + f0) = pack4(g0, g1, g2, g3);
            ps0 += g0; ps1 += g1; ps2 += g2; ps3 += g3;
            pq0 += g0 * g0; pq1 += g1 * g1; pq2 += g2 * g2; pq3 += g3 * g3;
        }
    }

    s_sum[wave][f0] = ps0; s_sum[wave][f0 + 1] = ps1;
    s_sum[wave][f0 + 2] = ps2; s_sum[wave][f0 + 3] = ps3;
    s_sq[wave][f0] = pq0; s_sq[wave][f0 + 1] = pq1;
    s_sq[wave][f0 + 2] = pq2; s_sq[wave][f0 + 3] = pq3;
    __syncthreads();

    int f = threadIdx.x;
    float ts = s_sum[0][f] + s_sum[1][f] + s_sum[2][f] + s_sum[3][f];
    float tq = s_sq[0][f] + s_sq[1][f] + s_sq[2][f] + s_sq[3][f];
    atomicAdd(&stats[f], ts);
    atomicAdd(&stats[256 + f], tq);
}

__global__ void bnfin_kernel(const float* __restrict__ stats, const float* __restrict__ g,
                             const float* __restrict__ b, float* __restrict__ ss, int N) {
    int f = threadIdx.x;
    float inv_n = 1.0f / (float)N;
    float mean = stats[f] * inv_n;
    float var = stats[256 + f] * inv_n - mean * mean;
    float rstd = rsqrtf(var + 1e-5f);
    float sc = g[f] * rstd;
    ss[f] = sc;
    ss[256 + f] = b[f] - mean * sc;
}

__global__ void elem_kernel(const unsigned short* __restrict__ agg, const float* __restrict__ ss,
                            unsigned short* __restrict__ h, size_t total) {
    size_t i = ((size_t)blockIdx.x * 256 + threadIdx.x) * 4;
    if (i < total) {
        float a0, a1, a2, a3;
        unpack4(*reinterpret_cast<const uint2*>(agg + i), a0, a1, a2, a3);
        int f = (int)(i & 255);
        float r0 = fmaxf(a0 * ss[f] + ss[256 + f], 0.0f);
        float r1 = fmaxf(a1 * ss[f + 1] + ss[256 + f + 1], 0.0f);
        float r2 = fmaxf(a2 * ss[f + 2] + ss[256 + f + 2], 0.0f);
        float r3 = fmaxf(a3 * ss[f + 3] + ss[256 + f + 3], 0.0f);
        *reinterpret_cast<uint2*>(h + i) = pack4(r0, r1, r2, r3);
    }
}

// ---------------- global_add_pool (batch is sorted) ----------------

__global__ __launch_bounds__(256)
void pool_kernel(const unsigned short* __restrict__ h, const int* __restrict__ batch,
                 float* __restrict__ g, int N) {
    __shared__ int sb[256];
    int f = threadIdx.x;
    int r0 = blockIdx.x * 256;
    int rows = min(256, N - r0);
    sb[f] = (r0 + f < N) ? batch[r0 + f] : -1;
    __syncthreads();
    float acc = 0.0f;
    int cur = sb[0];
    for (int t = 0; t < rows; t++) {
        int b = sb[t];
        if (b != cur) {
            atomicAdd(&g[cur * 256 + f], acc);
            acc = 0.0f;
            cur = b;
        }
        acc += bf2f(h[(size_t)(r0 + t) * 256 + f]);
    }
    atomicAdd(&g[cur * 256 + f], acc);
}

// ---------------- head MLP: relu(g@w1+b1)@w2+b2 ----------------

__global__ void head_kernel(const float* __restrict__ g, const float* __restrict__ w1,
                            const float* __restrict__ b1, const float* __restrict__ w2,
                            const float* __restrict__ b2, float* __restrict__ out) {
    __shared__ float gr[256];
    __shared__ float z[128];
    int b = blockIdx.x, t = threadIdx.x;
    gr[t] = g[b * 256 + t];
    gr[t + 128] = g[b * 256 + 128 + t];
    __syncthreads();
    float acc = b1[t];
    for (int k = 0; k < 256; k++) acc += gr[k] * w1[k * 128 + t];
    z[t] = fmaxf(acc, 0.0f);
    __syncthreads();
    if (t < 12) {
        float o = b2[t];
        for (int k = 0; k < 128; k++) o += z[k] * w2[k * 12 + t];
        out[b * 12 + t] = o;
    }
}

// ---------------- launch ----------------

extern "C" void kernel_launch(void* const* d_in, const int* in_sizes, int n_in,
                              void* d_out, int out_size, void* d_ws, size_t ws_size,
                              hipStream_t stream) {
    const float* x      = (const float*)d_in[0];
    const int*   ei     = (const int*)d_in[1];
    const int*   batch  = (const int*)d_in[2];
    const float* node_w = (const float*)d_in[3];
    const float* node_b = (const float*)d_in[4];
    const float* conv_w = (const float*)d_in[5];
    const float* conv_b = (const float*)d_in[6];
    const float* bn_g   = (const float*)d_in[7];
    const float* bn_b   = (const float*)d_in[8];
    const float* hw1    = (const float*)d_in[9];
    const float* hb1    = (const float*)d_in[10];
    const float* hw2    = (const float*)d_in[11];
    const float* hb2    = (const float*)d_in[12];
    float* out = (float*)d_out;

    const int N = in_sizes[2];
    const int E = in_sizes[1] / 2;
    const int IN = 64, H = 256, L = 3;

    char* base = (char*)d_ws;
    size_t off = 0;
    auto alloc = [&](size_t bytes) -> void* {
        off = (off + 255) & ~(size_t)255;
        void* p = base + off;
        off += bytes;
        return p;
    };
    unsigned short* xbf = (unsigned short*)alloc((size_t)N * IN * 2);
    unsigned short* h   = (unsigned short*)alloc((size_t)N * H * 2);
    unsigned short* hws = (unsigned short*)alloc((size_t)(N + 1) * H * 2);  // +1 zero row
    unsigned short* agg = (unsigned short*)alloc((size_t)N * H * 2);
    unsigned short* nwT = (unsigned short*)alloc((size_t)IN * H * 2);
    unsigned short* cwT = (unsigned short*)alloc((size_t)L * H * H * 2);
    int* cnt      = (int*)alloc((size_t)N * 4);
    int* fill     = (int*)alloc((size_t)N * 4);
    int* rowstart = (int*)alloc((size_t)(N + 1) * 4);
    int* scanbuf  = (int*)alloc((size_t)N * 4);
    int* bsum     = (int*)alloc(1024);
    int* boff     = (int*)alloc(1024);
    int* eidx     = (int*)alloc((size_t)E * 4);
    float* dis    = (float*)alloc((size_t)N * 4);
    float* stats  = (float*)alloc(512 * 4);
    float* ss     = (float*)alloc(512 * 4);
    float* gpool  = (float*)alloc(64 * H * 4);

    const int* row = ei;
    const int* col = ei + E;

    hipMemsetAsync(cnt, 0, (size_t)N * 4, stream);
    hipMemsetAsync(fill, 0, (size_t)N * 4, stream);
    zrow_kernel<<<dim3(1), 256, 0, stream>>>(hws + (size_t)N * H);

    cvt_x_kernel<<<dim3((N * IN / 4 + 255) / 256), 256, 0, stream>>>(x, xbf, N * IN);
    tr_node_kernel<<<dim3((IN * H + 255) / 256), 256, 0, stream>>>(node_w, nwT);
    tr_conv_kernel<<<dim3((L * H * H + 255) / 256), 256, 0, stream>>>(conv_w, cwT);

    deg_kernel<<<dim3((E + 255) / 256), 256, 0, stream>>>(col, cnt, E);
    dis_kernel<<<dim3((N + 255) / 256), 256, 0, stream>>>(cnt, dis, N);
    int nb = (N + 511) / 512;
    scan1_kernel<<<dim3(nb), 512, 0, stream>>>(cnt, scanbuf, bsum, N);
    scan2_kernel<<<dim3(1), 64, 0, stream>>>(bsum, boff, nb);
    scan3_kernel<<<dim3((N + 255) / 256), 256, 0, stream>>>(scanbuf, boff, rowstart, N);
    scatter_kernel<<<dim3((E + 255) / 256), 256, 0, stream>>>(row, col, rowstart, fill, eidx, E);

    dim3 gg((N + 127) / 128, H / 128);
    gemm_bt_kernel<<<gg, 256, 0, stream>>>(xbf, nwT, h, node_b, nullptr, N, IN, H);

    for (int l = 0; l < L; l++) {
        // hws = dis[v] * (h @ conv_w[l])  (scale fused into epilogue)
        gemm_bt_kernel<<<gg, 256, 0, stream>>>(h, cwT + (size_t)l * H * H, hws, nullptr, dis, N, H, H);
        hipMemsetAsync(stats, 0, 512 * 4, stream);
        agg_kernel<<<dim3((N + 15) / 16), 256, 0, stream>>>(hws, rowstart, eidx, dis,
                                                            conv_b + l * H, agg, stats, N);
        bnfin_kernel<<<dim3(1), 256, 0, stream>>>(stats, bn_g + l * H, bn_b + l * H, ss, N);
        size_t total = (size_t)N * H;
        elem_kernel<<<dim3((int)((total / 4 + 255) / 256)), 256, 0, stream>>>(agg, ss, h, total);
    }

    hipMemsetAsync(gpool, 0, 64 * H * 4, stream);
    pool_kernel<<<dim3((N + 255) / 256), 256, 0, stream>>>(h, batch, gpool, N);
    head_kernel<<<dim3(64), 128, 0, stream>>>(gpool, hw1, hb1, hw2, hb2, out);
}

// Round 3
// 720.283 us; speedup vs baseline: 1.1928x; 1.0330x over previous
//
#include <hip/hip_runtime.h>
#include <stdint.h>

typedef __bf16 bf16x8 __attribute__((ext_vector_type(8)));
typedef float f32x4 __attribute__((ext_vector_type(4)));

__device__ __forceinline__ float bf2f(unsigned short u) {
    return __uint_as_float(((unsigned)u) << 16);
}
__device__ __forceinline__ unsigned short f2bf(float f) {
    unsigned u = __float_as_uint(f);
    unsigned r = u + 0x7fffu + ((u >> 16) & 1u);  // RNE
    return (unsigned short)(r >> 16);
}
__device__ __forceinline__ void unpack4(uint2 u, float& a, float& b, float& c, float& d) {
    a = __uint_as_float(u.x << 16);
    b = __uint_as_float(u.x & 0xffff0000u);
    c = __uint_as_float(u.y << 16);
    d = __uint_as_float(u.y & 0xffff0000u);
}
__device__ __forceinline__ uint2 pack4(float a, float b, float c, float d) {
    uint2 o;
    o.x = (unsigned)f2bf(a) | ((unsigned)f2bf(b) << 16);
    o.y = (unsigned)f2bf(c) | ((unsigned)f2bf(d) << 16);
    return o;
}

// ---------------- conversion / transpose ----------------

__global__ void cvt_x_kernel(const float* __restrict__ x, unsigned short* __restrict__ xbf, int n) {
    int i = (blockIdx.x * 256 + threadIdx.x) * 4;
    if (i < n) {
        float4 v = *reinterpret_cast<const float4*>(x + i);
        *reinterpret_cast<uint2*>(xbf + i) = pack4(v.x, v.y, v.z, v.w);
    }
}

__global__ void tr_node_kernel(const float* __restrict__ w, unsigned short* __restrict__ wT) {
    int idx = blockIdx.x * 256 + threadIdx.x;  // over 64*256
    if (idx < 64 * 256) {
        int k = idx >> 8, n = idx & 255;
        wT[n * 64 + k] = f2bf(w[idx]);
    }
}

__global__ void tr_conv_kernel(const float* __restrict__ w, unsigned short* __restrict__ wT) {
    int idx = blockIdx.x * 256 + threadIdx.x;  // over 3*256*256
    if (idx < 3 * 256 * 256) {
        int l = idx >> 16, rem = idx & 65535;
        int k = rem >> 8, n = rem & 255;
        wT[(l << 16) + (n << 8) + k] = f2bf(w[idx]);
    }
}

// ---------------- degree / CSR build ----------------

__global__ void deg_kernel(const int* __restrict__ col, int* __restrict__ cnt, int E) {
    int e = blockIdx.x * 256 + threadIdx.x;
    if (e < E) atomicAdd(&cnt[col[e]], 1);
}

__global__ void dis_kernel(const int* __restrict__ cnt, float* __restrict__ dis, int N) {
    int v = blockIdx.x * 256 + threadIdx.x;
    if (v < N) dis[v] = rsqrtf((float)cnt[v] + 1.0f);  // +1 self-loop
}

__global__ void scan1_kernel(const int* __restrict__ cnt, int* __restrict__ scanbuf,
                             int* __restrict__ bsum, int N) {
    __shared__ int s[512];
    int i = blockIdx.x * 512 + threadIdx.x;
    s[threadIdx.x] = (i < N) ? cnt[i] : 0;
    __syncthreads();
    for (int off = 1; off < 512; off <<= 1) {
        int t = (threadIdx.x >= off) ? s[threadIdx.x - off] : 0;
        __syncthreads();
        s[threadIdx.x] += t;
        __syncthreads();
    }
    if (i < N) scanbuf[i] = s[threadIdx.x];
    if (threadIdx.x == 511) bsum[blockIdx.x] = s[511];
}

__global__ void scan2_kernel(const int* __restrict__ bsum, int* __restrict__ boff, int nb) {
    if (threadIdx.x == 0 && blockIdx.x == 0) {
        int acc = 0;
        for (int b = 0; b < nb; b++) { boff[b] = acc; acc += bsum[b]; }
    }
}

__global__ void scan3_kernel(const int* __restrict__ scanbuf, const int* __restrict__ boff,
                             int* __restrict__ rowstart, int N) {
    int i = blockIdx.x * 256 + threadIdx.x;
    if (i < N) rowstart[i + 1] = scanbuf[i] + boff[i >> 9];
    if (i == 0) rowstart[0] = 0;
}

__global__ void scatter_kernel(const int* __restrict__ row, const int* __restrict__ col,
                               const int* __restrict__ rowstart, int* __restrict__ fill,
                               int* __restrict__ eidx, int E) {
    int e = blockIdx.x * 256 + threadIdx.x;
    if (e < E) {
        int c = col[e];
        int pos = rowstart[c] + atomicAdd(&fill[c], 1);
        eidx[pos] = row[e];
    }
}

__global__ void zrow_kernel(unsigned short* __restrict__ p) {
    p[threadIdx.x] = 0;  // 256-wide zero row
}

// ---------------- GEMM: C[M,Nc] = A[M,K] * B[K,Nc], B given transposed (BT[Nc,K]) ----------------
// bf16 inputs, fp32 MFMA accumulate, bf16 out. Optional fp32 bias[nc] and per-row scale[mr].
// Block 256 thr = 4 waves (2x2), block tile 128x128, wave tile 64x64 (4x4 of 16x16x32 MFMA).

__global__ __launch_bounds__(256)
void gemm_bt_kernel(const unsigned short* __restrict__ A, const unsigned short* __restrict__ BT,
                    unsigned short* __restrict__ C, const float* __restrict__ bias,
                    const float* __restrict__ scale, int M, int K, int Nc) {
    const int lane = threadIdx.x & 63;
    const int wave = threadIdx.x >> 6;
    const int wm = wave >> 1, wn = wave & 1;
    const int r = lane & 15, q = lane >> 4;
    const int m0 = blockIdx.x * 128 + wm * 64;
    const int n0 = blockIdx.y * 128 + wn * 64;

    f32x4 acc[4][4] = {};

    for (int k0 = 0; k0 < K; k0 += 32) {
        bf16x8 a[4], b[4];
#pragma unroll
        for (int i = 0; i < 4; i++) {
            int mr = m0 + i * 16 + r;
            if (mr >= M) mr = M - 1;  // clamp; masked at store
            a[i] = *reinterpret_cast<const bf16x8*>(A + (size_t)mr * K + k0 + q * 8);
        }
#pragma unroll
        for (int j = 0; j < 4; j++) {
            int nr = n0 + j * 16 + r;
            b[j] = *reinterpret_cast<const bf16x8*>(BT + (size_t)nr * K + k0 + q * 8);
        }
#pragma unroll
        for (int i = 0; i < 4; i++)
#pragma unroll
            for (int j = 0; j < 4; j++)
                acc[i][j] = __builtin_amdgcn_mfma_f32_16x16x32_bf16(a[i], b[j], acc[i][j], 0, 0, 0);
    }

#pragma unroll
    for (int i = 0; i < 4; i++) {
#pragma unroll
        for (int t = 0; t < 4; t++) {
            int mr = m0 + i * 16 + q * 4 + t;  // C/D: row = q*4+reg, col = lane&15
            if (mr < M) {
                float rs = scale ? scale[mr] : 1.0f;
#pragma unroll
                for (int j = 0; j < 4; j++) {
                    int nc = n0 + j * 16 + r;
                    float v = acc[i][j][t] * rs;
                    if (bias) v += bias[nc];
                    C[(size_t)mr * Nc + nc] = f2bf(v);
                }
            }
        }
    }
}

// ---------------- aggregation (GCN message passing) + fused BN stats ----------------
// hws[v] = dis[v] * (h @ W)[v]  (pre-scaled in GEMM epilogue); hws[N] is a zero row.
// agg[v] = conv_b + dis[v] * ( hws[v] + sum_{e: col=v} hws[src] )
// Block 256 thr = 4 waves; each wave handles 4 nodes; lane owns 4 features.
// Neighbor loop: coalesced 64-index chunk + shfl broadcast; group count padded to a
// multiple of 16 (zero row absorbs pads) so the body is a FIXED fully-unrolled
// 16-load block -> 16 loads in flight per wave.

__global__ __launch_bounds__(256)
void agg_kernel(const unsigned short* __restrict__ hws, const int* __restrict__ rowstart,
                const int* __restrict__ eidx, const float* __restrict__ dis,
                const float* __restrict__ cb, unsigned short* __restrict__ agg,
                float* __restrict__ stats, int N) {
    __shared__ float s_sum[4][256];
    __shared__ float s_sq[4][256];
    const int lane = threadIdx.x & 63;
    const int wave = threadIdx.x >> 6;
    const int f0 = lane * 4;

    const float c0 = cb[f0], c1 = cb[f0 + 1], c2 = cb[f0 + 2], c3 = cb[f0 + 3];
    float ps0 = 0, ps1 = 0, ps2 = 0, ps3 = 0;
    float pq0 = 0, pq1 = 0, pq2 = 0, pq3 = 0;

#pragma unroll
    for (int s = 0; s < 4; s++) {
        int v = blockIdx.x * 16 + wave * 4 + s;
        if (v < N) {
            float dv = dis[v];
            float x0, x1, x2, x3;
            uint2 raw = *reinterpret_cast<const uint2*>(hws + (size_t)v * 256 + f0);
            unpack4(raw, x0, x1, x2, x3);
            float a0 = x0, a1 = x1, a2 = x2, a3 = x3;

            int js = rowstart[v], je = rowstart[v + 1];
            int deg = je - js;
            for (int base = 0; base < deg; base += 64) {
                int cn = min(64, deg - base);
                int myidx = (lane < cn) ? eidx[js + base + lane] : N;  // N -> zero row
                int cnr = (cn + 15) & ~15;                             // pad to 16
                for (int t = 0; t < cnr; t += 16) {
                    uint2 rr[16];
#pragma unroll
                    for (int k = 0; k < 16; k++) {
                        int u = __shfl(myidx, t + k);
                        rr[k] = *reinterpret_cast<const uint2*>(hws + (size_t)u * 256 + f0);
                    }
#pragma unroll
                    for (int k = 0; k < 16; k++) {
                        unpack4(rr[k], x0, x1, x2, x3);
                        a0 += x0; a1 += x1; a2 += x2; a3 += x3;
                    }
                }
            }

            float g0 = c0 + dv * a0, g1 = c1 + dv * a1;
            float g2 = c2 + dv * a2, g3 = c3 + dv * a3;
            *reinterpret_cast<uint2*>(agg + (size_t)v * 256 + f0) = pack4(g0, g1, g2, g3);
            ps0 += g0; ps1 += g1; ps2 += g2; ps3 += g3;
            pq0 += g0 * g0; pq1 += g1 * g1; pq2 += g2 * g2; pq3 += g3 * g3;
        }
    }

    s_sum[wave][f0] = ps0; s_sum[wave][f0 + 1] = ps1;
    s_sum[wave][f0 + 2] = ps2; s_sum[wave][f0 + 3] = ps3;
    s_sq[wave][f0] = pq0; s_sq[wave][f0 + 1] = pq1;
    s_sq[wave][f0 + 2] = pq2; s_sq[wave][f0 + 3] = pq3;
    __syncthreads();

    int f = threadIdx.x;
    float ts = s_sum[0][f] + s_sum[1][f] + s_sum[2][f] + s_sum[3][f];
    float tq = s_sq[0][f] + s_sq[1][f] + s_sq[2][f] + s_sq[3][f];
    atomicAdd(&stats[f], ts);
    atomicAdd(&stats[256 + f], tq);
}

__global__ void bnfin_kernel(const float* __restrict__ stats, const float* __restrict__ g,
                             const float* __restrict__ b, float* __restrict__ ss, int N) {
    int f = threadIdx.x;
    float inv_n = 1.0f / (float)N;
    float mean = stats[f] * inv_n;
    float var = stats[256 + f] * inv_n - mean * mean;
    float rstd = rsqrtf(var + 1e-5f);
    float sc = g[f] * rstd;
    ss[f] = sc;
    ss[256 + f] = b[f] - mean * sc;
}

__global__ void elem_kernel(const unsigned short* __restrict__ agg, const float* __restrict__ ss,
                            unsigned short* __restrict__ h, size_t total) {
    size_t i = ((size_t)blockIdx.x * 256 + threadIdx.x) * 4;
    if (i < total) {
        float a0, a1, a2, a3;
        unpack4(*reinterpret_cast<const uint2*>(agg + i), a0, a1, a2, a3);
        int f = (int)(i & 255);
        float r0 = fmaxf(a0 * ss[f] + ss[256 + f], 0.0f);
        float r1 = fmaxf(a1 * ss[f + 1] + ss[256 + f + 1], 0.0f);
        float r2 = fmaxf(a2 * ss[f + 2] + ss[256 + f + 2], 0.0f);
        float r3 = fmaxf(a3 * ss[f + 3] + ss[256 + f + 3], 0.0f);
        *reinterpret_cast<uint2*>(h + i) = pack4(r0, r1, r2, r3);
    }
}

// ---------------- global_add_pool (batch is sorted) ----------------

__global__ __launch_bounds__(256)
void pool_kernel(const unsigned short* __restrict__ h, const int* __restrict__ batch,
                 float* __restrict__ g, int N) {
    __shared__ int sb[256];
    int f = threadIdx.x;
    int r0 = blockIdx.x * 256;
    int rows = min(256, N - r0);
    sb[f] = (r0 + f < N) ? batch[r0 + f] : -1;
    __syncthreads();
    float acc = 0.0f;
    int cur = sb[0];
    for (int t = 0; t < rows; t++) {
        int b = sb[t];
        if (b != cur) {
            atomicAdd(&g[cur * 256 + f], acc);
            acc = 0.0f;
            cur = b;
        }
        acc += bf2f(h[(size_t)(r0 + t) * 256 + f]);
    }
    atomicAdd(&g[cur * 256 + f], acc);
}

// ---------------- head MLP: relu(g@w1+b1)@w2+b2 ----------------

__global__ void head_kernel(const float* __restrict__ g, const float* __restrict__ w1,
                            const float* __restrict__ b1, const float* __restrict__ w2,
                            const float* __restrict__ b2, float* __restrict__ out) {
    __shared__ float gr[256];
    __shared__ float z[128];
    int b = blockIdx.x, t = threadIdx.x;
    gr[t] = g[b * 256 + t];
    gr[t + 128] = g[b * 256 + 128 + t];
    __syncthreads();
    float acc = b1[t];
    for (int k = 0; k < 256; k++) acc += gr[k] * w1[k * 128 + t];
    z[t] = fmaxf(acc, 0.0f);
    __syncthreads();
    if (t < 12) {
        float o = b2[t];
        for (int k = 0; k < 128; k++) o += z[k] * w2[k * 12 + t];
        out[b * 12 + t] = o;
    }
}

// ---------------- launch ----------------

extern "C" void kernel_launch(void* const* d_in, const int* in_sizes, int n_in,
                              void* d_out, int out_size, void* d_ws, size_t ws_size,
                              hipStream_t stream) {
    const float* x      = (const float*)d_in[0];
    const int*   ei     = (const int*)d_in[1];
    const int*   batch  = (const int*)d_in[2];
    const float* node_w = (const float*)d_in[3];
    const float* node_b = (const float*)d_in[4];
    const float* conv_w = (const float*)d_in[5];
    const float* conv_b = (const float*)d_in[6];
    const float* bn_g   = (const float*)d_in[7];
    const float* bn_b   = (const float*)d_in[8];
    const float* hw1    = (const float*)d_in[9];
    const float* hb1    = (const float*)d_in[10];
    const float* hw2    = (const float*)d_in[11];
    const float* hb2    = (const float*)d_in[12];
    float* out = (float*)d_out;

    const int N = in_sizes[2];
    const int E = in_sizes[1] / 2;
    const int IN = 64, H = 256, L = 3;

    char* base = (char*)d_ws;
    size_t off = 0;
    auto alloc = [&](size_t bytes) -> void* {
        off = (off + 255) & ~(size_t)255;
        void* p = base + off;
        off += bytes;
        return p;
    };
    unsigned short* xbf = (unsigned short*)alloc((size_t)N * IN * 2);
    unsigned short* h   = (unsigned short*)alloc((size_t)N * H * 2);
    unsigned short* hws = (unsigned short*)alloc((size_t)(N + 1) * H * 2);  // +1 zero row
    unsigned short* agg = (unsigned short*)alloc((size_t)N * H * 2);
    unsigned short* nwT = (unsigned short*)alloc((size_t)IN * H * 2);
    unsigned short* cwT = (unsigned short*)alloc((size_t)L * H * H * 2);
    int* cnt      = (int*)alloc((size_t)N * 4);
    int* fill     = (int*)alloc((size_t)N * 4);
    int* rowstart = (int*)alloc((size_t)(N + 1) * 4);
    int* scanbuf  = (int*)alloc((size_t)N * 4);
    int* bsum     = (int*)alloc(1024);
    int* boff     = (int*)alloc(1024);
    int* eidx     = (int*)alloc((size_t)E * 4);
    float* dis    = (float*)alloc((size_t)N * 4);
    float* stats  = (float*)alloc(512 * 4);
    float* ss     = (float*)alloc(512 * 4);
    float* gpool  = (float*)alloc(64 * H * 4);

    const int* row = ei;
    const int* col = ei + E;

    hipMemsetAsync(cnt, 0, (size_t)N * 4, stream);
    hipMemsetAsync(fill, 0, (size_t)N * 4, stream);
    zrow_kernel<<<dim3(1), 256, 0, stream>>>(hws + (size_t)N * H);

    cvt_x_kernel<<<dim3((N * IN / 4 + 255) / 256), 256, 0, stream>>>(x, xbf, N * IN);
    tr_node_kernel<<<dim3((IN * H + 255) / 256), 256, 0, stream>>>(node_w, nwT);
    tr_conv_kernel<<<dim3((L * H * H + 255) / 256), 256, 0, stream>>>(conv_w, cwT);

    deg_kernel<<<dim3((E + 255) / 256), 256, 0, stream>>>(col, cnt, E);
    dis_kernel<<<dim3((N + 255) / 256), 256, 0, stream>>>(cnt, dis, N);
    int nb = (N + 511) / 512;
    scan1_kernel<<<dim3(nb), 512, 0, stream>>>(cnt, scanbuf, bsum, N);
    scan2_kernel<<<dim3(1), 64, 0, stream>>>(bsum, boff, nb);
    scan3_kernel<<<dim3((N + 255) / 256), 256, 0, stream>>>(scanbuf, boff, rowstart, N);
    scatter_kernel<<<dim3((E + 255) / 256), 256, 0, stream>>>(row, col, rowstart, fill, eidx, E);

    dim3 gg((N + 127) / 128, H / 128);
    gemm_bt_kernel<<<gg, 256, 0, stream>>>(xbf, nwT, h, node_b, nullptr, N, IN, H);

    for (int l = 0; l < L; l++) {
        // hws = dis[v] * (h @ conv_w[l])  (scale fused into epilogue)
        gemm_bt_kernel<<<gg, 256, 0, stream>>>(h, cwT + (size_t)l * H * H, hws, nullptr, dis, N, H, H);
        hipMemsetAsync(stats, 0, 512 * 4, stream);
        agg_kernel<<<dim3((N + 15) / 16), 256, 0, stream>>>(hws, rowstart, eidx, dis,
                                                            conv_b + l * H, agg, stats, N);
        bnfin_kernel<<<dim3(1), 256, 0, stream>>>(stats, bn_g + l * H, bn_b + l * H, ss, N);
        size_t total = (size_t)N * H;
        elem_kernel<<<dim3((int)((total / 4 + 255) / 256)), 256, 0, stream>>>(agg, ss, h, total);
    }

    hipMemsetAsync(gpool, 0, 64 * H * 4, stream);
    pool_kernel<<<dim3((N + 255) / 256), 256, 0, stream>>>(h, batch, gpool, N);
    head_kernel<<<dim3(64), 128, 0, stream>>>(gpool, hw1, hb1, hw2, hb2, out);
}

// Round 4
// 699.466 us; speedup vs baseline: 1.2283x; 1.0298x over previous
//
#include <hip/hip_runtime.h>
#include <stdint.h>

typedef __bf16 bf16x8 __attribute__((ext_vector_type(8)));
typedef float f32x4 __attribute__((ext_vector_type(4)));

__device__ __forceinline__ float bf2f(unsigned short u) {
    return __uint_as_float(((unsigned)u) << 16);
}
__device__ __forceinline__ unsigned short f2bf(float f) {
    unsigned u = __float_as_uint(f);
    unsigned r = u + 0x7fffu + ((u >> 16) & 1u);  // RNE
    return (unsigned short)(r >> 16);
}
__device__ __forceinline__ void unpack4(uint2 u, float& a, float& b, float& c, float& d) {
    a = __uint_as_float(u.x << 16);
    b = __uint_as_float(u.x & 0xffff0000u);
    c = __uint_as_float(u.y << 16);
    d = __uint_as_float(u.y & 0xffff0000u);
}
__device__ __forceinline__ uint2 pack4(float a, float b, float c, float d) {
    uint2 o;
    o.x = (unsigned)f2bf(a) | ((unsigned)f2bf(b) << 16);
    o.y = (unsigned)f2bf(c) | ((unsigned)f2bf(d) << 16);
    return o;
}

// ---------------- conversion / transpose ----------------

__global__ void cvt_x_kernel(const float* __restrict__ x, unsigned short* __restrict__ xbf, int n) {
    int i = (blockIdx.x * 256 + threadIdx.x) * 4;
    if (i < n) {
        float4 v = *reinterpret_cast<const float4*>(x + i);
        *reinterpret_cast<uint2*>(xbf + i) = pack4(v.x, v.y, v.z, v.w);
    }
}

__global__ void tr_node_kernel(const float* __restrict__ w, unsigned short* __restrict__ wT) {
    int idx = blockIdx.x * 256 + threadIdx.x;  // over 64*256
    if (idx < 64 * 256) {
        int k = idx >> 8, n = idx & 255;
        wT[n * 64 + k] = f2bf(w[idx]);
    }
}

__global__ void tr_conv_kernel(const float* __restrict__ w, unsigned short* __restrict__ wT) {
    int idx = blockIdx.x * 256 + threadIdx.x;  // over 3*256*256
    if (idx < 3 * 256 * 256) {
        int l = idx >> 16, rem = idx & 65535;
        int k = rem >> 8, n = rem & 255;
        wT[(l << 16) + (n << 8) + k] = f2bf(w[idx]);
    }
}

// ---------------- degree / CSR build ----------------

__global__ void deg_kernel(const int* __restrict__ col, int* __restrict__ cnt, int E) {
    int e = blockIdx.x * 256 + threadIdx.x;
    if (e < E) atomicAdd(&cnt[col[e]], 1);
}

__global__ void dis_kernel(const int* __restrict__ cnt, float* __restrict__ dis, int N) {
    int v = blockIdx.x * 256 + threadIdx.x;
    if (v < N) dis[v] = rsqrtf((float)cnt[v] + 1.0f);  // +1 self-loop
}

__global__ void scan1_kernel(const int* __restrict__ cnt, int* __restrict__ scanbuf,
                             int* __restrict__ bsum, int N) {
    __shared__ int s[512];
    int i = blockIdx.x * 512 + threadIdx.x;
    s[threadIdx.x] = (i < N) ? cnt[i] : 0;
    __syncthreads();
    for (int off = 1; off < 512; off <<= 1) {
        int t = (threadIdx.x >= off) ? s[threadIdx.x - off] : 0;
        __syncthreads();
        s[threadIdx.x] += t;
        __syncthreads();
    }
    if (i < N) scanbuf[i] = s[threadIdx.x];
    if (threadIdx.x == 511) bsum[blockIdx.x] = s[511];
}

__global__ void scan2_kernel(const int* __restrict__ bsum, int* __restrict__ boff, int nb) {
    if (threadIdx.x == 0 && blockIdx.x == 0) {
        int acc = 0;
        for (int b = 0; b < nb; b++) { boff[b] = acc; acc += bsum[b]; }
    }
}

__global__ void scan3_kernel(const int* __restrict__ scanbuf, const int* __restrict__ boff,
                             int* __restrict__ rowstart, int N) {
    int i = blockIdx.x * 256 + threadIdx.x;
    if (i < N) rowstart[i + 1] = scanbuf[i] + boff[i >> 9];
    if (i == 0) rowstart[0] = 0;
}

__global__ void scatter_kernel(const int* __restrict__ row, const int* __restrict__ col,
                               const int* __restrict__ rowstart, int* __restrict__ fill,
                               int* __restrict__ eidx, int E) {
    int e = blockIdx.x * 256 + threadIdx.x;
    if (e < E) {
        int c = col[e];
        int pos = rowstart[c] + atomicAdd(&fill[c], 1);
        eidx[pos] = row[e];
    }
}

__global__ void zrow_kernel(unsigned short* __restrict__ p) {
    p[threadIdx.x] = 0;  // 256-wide zero row
}

// ---------------- GEMM: C[M,Nc] = A[M,K] * B[K,Nc], B given transposed (BT[Nc,K]) ----------------

__global__ __launch_bounds__(256)
void gemm_bt_kernel(const unsigned short* __restrict__ A, const unsigned short* __restrict__ BT,
                    unsigned short* __restrict__ C, const float* __restrict__ bias,
                    const float* __restrict__ scale, int M, int K, int Nc) {
    const int lane = threadIdx.x & 63;
    const int wave = threadIdx.x >> 6;
    const int wm = wave >> 1, wn = wave & 1;
    const int r = lane & 15, q = lane >> 4;
    const int m0 = blockIdx.x * 128 + wm * 64;
    const int n0 = blockIdx.y * 128 + wn * 64;

    f32x4 acc[4][4] = {};

    for (int k0 = 0; k0 < K; k0 += 32) {
        bf16x8 a[4], b[4];
#pragma unroll
        for (int i = 0; i < 4; i++) {
            int mr = m0 + i * 16 + r;
            if (mr >= M) mr = M - 1;  // clamp; masked at store
            a[i] = *reinterpret_cast<const bf16x8*>(A + (size_t)mr * K + k0 + q * 8);
        }
#pragma unroll
        for (int j = 0; j < 4; j++) {
            int nr = n0 + j * 16 + r;
            b[j] = *reinterpret_cast<const bf16x8*>(BT + (size_t)nr * K + k0 + q * 8);
        }
#pragma unroll
        for (int i = 0; i < 4; i++)
#pragma unroll
            for (int j = 0; j < 4; j++)
                acc[i][j] = __builtin_amdgcn_mfma_f32_16x16x32_bf16(a[i], b[j], acc[i][j], 0, 0, 0);
    }

#pragma unroll
    for (int i = 0; i < 4; i++) {
#pragma unroll
        for (int t = 0; t < 4; t++) {
            int mr = m0 + i * 16 + q * 4 + t;  // C/D: row = q*4+reg, col = lane&15
            if (mr < M) {
                float rs = scale ? scale[mr] : 1.0f;
#pragma unroll
                for (int j = 0; j < 4; j++) {
                    int nc = n0 + j * 16 + r;
                    float v = acc[i][j][t] * rs;
                    if (bias) v += bias[nc];
                    C[(size_t)mr * Nc + nc] = f2bf(v);
                }
            }
        }
    }
}

// ---------------- aggregation (GCN message passing) + fused BN stats ----------------
// hws[v] = dis[v] * (h @ W)[v]; hws[N] is a zero row.
// agg[v] = conv_b + dis[v] * ( hws[v] + sum_{e: col=v} hws[src] )
// Wave handles 4 nodes. Half-wave layout: lane&31 owns 8 features (uint4 = 16 B),
// lane>>5 picks edge parity -> each wave-wide load covers 2 edges (1 KB).
// All node metadata (rowstart, dis -> scalar; eidx chunks, self rows -> vector)
// prefetched up front; gather batches ping-pong between two 8-deep uint4 buffers
// across nodes so ~8 KB stays in flight with no full vmcnt drains on the common path.

__global__ __launch_bounds__(256)
void agg_kernel(const unsigned short* __restrict__ hws, const int* __restrict__ rowstart,
                const int* __restrict__ eidx, const float* __restrict__ dis,
                const float* __restrict__ cb, unsigned short* __restrict__ agg,
                float* __restrict__ stats, int N) {
    __shared__ float s_sum[4][256];
    __shared__ float s_sq[4][256];
    const int lane = threadIdx.x & 63;
    const int wave = threadIdx.x >> 6;
    const int sub = lane >> 5;         // edge parity
    const int fl = (lane & 31) * 8;    // feature base (8 features per lane)

    const int vb = __builtin_amdgcn_readfirstlane(blockIdx.x * 16 + wave * 4);

    // scalar metadata (wave-uniform)
    int rs[5];
#pragma unroll
    for (int s = 0; s < 5; s++) rs[s] = rowstart[min(vb + s, N)];
    int js[4], de[4];
    float dvv[4];
#pragma unroll
    for (int s = 0; s < 4; s++) {
        js[s] = rs[s];
        de[s] = (vb + s < N) ? (rs[s + 1] - rs[s]) : 0;
        dvv[s] = (vb + s < N) ? dis[vb + s] : 0.0f;
    }

    // vector prefetch: first 64-chunk of edge indices per node, self rows
    int idx0 = (lane < de[0]) ? eidx[js[0] + lane] : N;
    int idx1 = (lane < de[1]) ? eidx[js[1] + lane] : N;
    int idx2 = (lane < de[2]) ? eidx[js[2] + lane] : N;
    int idx3 = (lane < de[3]) ? eidx[js[3] + lane] : N;
    uint4 sf[4];
#pragma unroll
    for (int s = 0; s < 4; s++)
        sf[s] = *reinterpret_cast<const uint4*>(hws + (size_t)min(vb + s, N) * 256 + fl);

    // per-lane bias slice
    float4 cbl = *reinterpret_cast<const float4*>(cb + fl);
    float4 cbh = *reinterpret_cast<const float4*>(cb + fl + 4);
    float c8[8] = {cbl.x, cbl.y, cbl.z, cbl.w, cbh.x, cbh.y, cbh.z, cbh.w};

    float ps[8] = {}, pq[8] = {};

    uint4 rA[8], rB[8];

    auto issue = [&](int myidx, uint4 (&rr)[8]) {
#pragma unroll
        for (int k = 0; k < 8; k++) {
            int u = __shfl(myidx, 2 * k + sub);
            rr[k] = *reinterpret_cast<const uint4*>(hws + (size_t)u * 256 + fl);
        }
    };

    auto consume = [&](int s, int js_s, int d, float dvs, int myidx, uint4 (&rr)[8]) {
        float a[8] = {};
#pragma unroll
        for (int k = 0; k < 8; k++) {
            float x0, x1, x2, x3;
            unpack4(make_uint2(rr[k].x, rr[k].y), x0, x1, x2, x3);
            a[0] += x0; a[1] += x1; a[2] += x2; a[3] += x3;
            unpack4(make_uint2(rr[k].z, rr[k].w), x0, x1, x2, x3);
            a[4] += x0; a[5] += x1; a[6] += x2; a[7] += x3;
        }
        // rest of first chunk (deg > 16), same buffer (rare)
        int cnp = min(64, (d + 15) & ~15);
        for (int t = 16; t < cnp; t += 16) {
#pragma unroll
            for (int k = 0; k < 8; k++) {
                int u = __shfl(myidx, t + 2 * k + sub);
                rr[k] = *reinterpret_cast<const uint4*>(hws + (size_t)u * 256 + fl);
            }
#pragma unroll
            for (int k = 0; k < 8; k++) {
                float x0, x1, x2, x3;
                unpack4(make_uint2(rr[k].x, rr[k].y), x0, x1, x2, x3);
                a[0] += x0; a[1] += x1; a[2] += x2; a[3] += x3;
                unpack4(make_uint2(rr[k].z, rr[k].w), x0, x1, x2, x3);
                a[4] += x0; a[5] += x1; a[6] += x2; a[7] += x3;
            }
        }
        // chunks beyond 64 edges (very rare)
        for (int base = 64; base < d; base += 64) {
            int mi = (base + lane < d) ? eidx[js_s + base + lane] : N;
            int cn2 = min(64, d - base);
            int cnp2 = (cn2 + 15) & ~15;
            for (int t = 0; t < cnp2; t += 16) {
#pragma unroll
                for (int k = 0; k < 8; k++) {
                    int u = __shfl(mi, t + 2 * k + sub);
                    rr[k] = *reinterpret_cast<const uint4*>(hws + (size_t)u * 256 + fl);
                }
#pragma unroll
                for (int k = 0; k < 8; k++) {
                    float x0, x1, x2, x3;
                    unpack4(make_uint2(rr[k].x, rr[k].y), x0, x1, x2, x3);
                    a[0] += x0; a[1] += x1; a[2] += x2; a[3] += x3;
                    unpack4(make_uint2(rr[k].z, rr[k].w), x0, x1, x2, x3);
                    a[4] += x0; a[5] += x1; a[6] += x2; a[7] += x3;
                }
            }
        }
        // combine halves (edge parity)
#pragma unroll
        for (int j = 0; j < 8; j++) a[j] += __shfl_xor(a[j], 32);
        // self + bias + scale
        float x0, x1, x2, x3;
        unpack4(make_uint2(sf[s].x, sf[s].y), x0, x1, x2, x3);
        a[0] += x0; a[1] += x1; a[2] += x2; a[3] += x3;
        unpack4(make_uint2(sf[s].z, sf[s].w), x0, x1, x2, x3);
        a[4] += x0; a[5] += x1; a[6] += x2; a[7] += x3;
        float g[8];
#pragma unroll
        for (int j = 0; j < 8; j++) g[j] = c8[j] + dvs * a[j];
        if (vb + s < N && sub == 0) {
            uint2 lo = pack4(g[0], g[1], g[2], g[3]);
            uint2 hi = pack4(g[4], g[5], g[6], g[7]);
            *reinterpret_cast<uint4*>(agg + (size_t)(vb + s) * 256 + fl) =
                make_uint4(lo.x, lo.y, hi.x, hi.y);
#pragma unroll
            for (int j = 0; j < 8; j++) { ps[j] += g[j]; pq[j] += g[j] * g[j]; }
        }
    };

    issue(idx0, rA);
    issue(idx1, rB);
    consume(0, js[0], de[0], dvv[0], idx0, rA);
    issue(idx2, rA);
    consume(1, js[1], de[1], dvv[1], idx1, rB);
    issue(idx3, rB);
    consume(2, js[2], de[2], dvv[2], idx2, rA);
    consume(3, js[3], de[3], dvv[3], idx3, rB);

    if (sub == 0) {
#pragma unroll
        for (int j = 0; j < 8; j++) {
            s_sum[wave][fl + j] = ps[j];
            s_sq[wave][fl + j] = pq[j];
        }
    }
    __syncthreads();

    int f = threadIdx.x;
    float ts = s_sum[0][f] + s_sum[1][f] + s_sum[2][f] + s_sum[3][f];
    float tq = s_sq[0][f] + s_sq[1][f] + s_sq[2][f] + s_sq[3][f];
    atomicAdd(&stats[f], ts);
    atomicAdd(&stats[256 + f], tq);
}

__global__ void bnfin_kernel(const float* __restrict__ stats, const float* __restrict__ g,
                             const float* __restrict__ b, float* __restrict__ ss, int N) {
    int f = threadIdx.x;
    float inv_n = 1.0f / (float)N;
    float mean = stats[f] * inv_n;
    float var = stats[256 + f] * inv_n - mean * mean;
    float rstd = rsqrtf(var + 1e-5f);
    float sc = g[f] * rstd;
    ss[f] = sc;
    ss[256 + f] = b[f] - mean * sc;
}

__global__ void elem_kernel(const unsigned short* __restrict__ agg, const float* __restrict__ ss,
                            unsigned short* __restrict__ h, size_t total) {
    size_t i = ((size_t)blockIdx.x * 256 + threadIdx.x) * 4;
    if (i < total) {
        float a0, a1, a2, a3;
        unpack4(*reinterpret_cast<const uint2*>(agg + i), a0, a1, a2, a3);
        int f = (int)(i & 255);
        float r0 = fmaxf(a0 * ss[f] + ss[256 + f], 0.0f);
        float r1 = fmaxf(a1 * ss[f + 1] + ss[256 + f + 1], 0.0f);
        float r2 = fmaxf(a2 * ss[f + 2] + ss[256 + f + 2], 0.0f);
        float r3 = fmaxf(a3 * ss[f + 3] + ss[256 + f + 3], 0.0f);
        *reinterpret_cast<uint2*>(h + i) = pack4(r0, r1, r2, r3);
    }
}

// ---------------- global_add_pool (batch is sorted) ----------------

__global__ __launch_bounds__(256)
void pool_kernel(const unsigned short* __restrict__ h, const int* __restrict__ batch,
                 float* __restrict__ g, int N) {
    __shared__ int sb[256];
    int f = threadIdx.x;
    int r0 = blockIdx.x * 256;
    int rows = min(256, N - r0);
    sb[f] = (r0 + f < N) ? batch[r0 + f] : -1;
    __syncthreads();
    float acc = 0.0f;
    int cur = sb[0];
    for (int t = 0; t < rows; t++) {
        int b = sb[t];
        if (b != cur) {
            atomicAdd(&g[cur * 256 + f], acc);
            acc = 0.0f;
            cur = b;
        }
        acc += bf2f(h[(size_t)(r0 + t) * 256 + f]);
    }
    atomicAdd(&g[cur * 256 + f], acc);
}

// ---------------- head MLP: relu(g@w1+b1)@w2+b2 ----------------

__global__ void head_kernel(const float* __restrict__ g, const float* __restrict__ w1,
                            const float* __restrict__ b1, const float* __restrict__ w2,
                            const float* __restrict__ b2, float* __restrict__ out) {
    __shared__ float gr[256];
    __shared__ float z[128];
    int b = blockIdx.x, t = threadIdx.x;
    gr[t] = g[b * 256 + t];
    gr[t + 128] = g[b * 256 + 128 + t];
    __syncthreads();
    float acc = b1[t];
    for (int k = 0; k < 256; k++) acc += gr[k] * w1[k * 128 + t];
    z[t] = fmaxf(acc, 0.0f);
    __syncthreads();
    if (t < 12) {
        float o = b2[t];
        for (int k = 0; k < 128; k++) o += z[k] * w2[k * 12 + t];
        out[b * 12 + t] = o;
    }
}

// ---------------- launch ----------------

extern "C" void kernel_launch(void* const* d_in, const int* in_sizes, int n_in,
                              void* d_out, int out_size, void* d_ws, size_t ws_size,
                              hipStream_t stream) {
    const float* x      = (const float*)d_in[0];
    const int*   ei     = (const int*)d_in[1];
    const int*   batch  = (const int*)d_in[2];
    const float* node_w = (const float*)d_in[3];
    const float* node_b = (const float*)d_in[4];
    const float* conv_w = (const float*)d_in[5];
    const float* conv_b = (const float*)d_in[6];
    const float* bn_g   = (const float*)d_in[7];
    const float* bn_b   = (const float*)d_in[8];
    const float* hw1    = (const float*)d_in[9];
    const float* hb1    = (const float*)d_in[10];
    const float* hw2    = (const float*)d_in[11];
    const float* hb2    = (const float*)d_in[12];
    float* out = (float*)d_out;

    const int N = in_sizes[2];
    const int E = in_sizes[1] / 2;
    const int IN = 64, H = 256, L = 3;

    char* base = (char*)d_ws;
    size_t off = 0;
    auto alloc = [&](size_t bytes) -> void* {
        off = (off + 255) & ~(size_t)255;
        void* p = base + off;
        off += bytes;
        return p;
    };
    unsigned short* xbf = (unsigned short*)alloc((size_t)N * IN * 2);
    unsigned short* h   = (unsigned short*)alloc((size_t)N * H * 2);
    unsigned short* hws = (unsigned short*)alloc((size_t)(N + 1) * H * 2);  // +1 zero row
    unsigned short* agg = (unsigned short*)alloc((size_t)N * H * 2);
    unsigned short* nwT = (unsigned short*)alloc((size_t)IN * H * 2);
    unsigned short* cwT = (unsigned short*)alloc((size_t)L * H * H * 2);
    int* cnt      = (int*)alloc((size_t)N * 4);
    int* fill     = (int*)alloc((size_t)N * 4);
    int* rowstart = (int*)alloc((size_t)(N + 1) * 4);
    int* scanbuf  = (int*)alloc((size_t)N * 4);
    int* bsum     = (int*)alloc(1024);
    int* boff     = (int*)alloc(1024);
    int* eidx     = (int*)alloc((size_t)E * 4);
    float* dis    = (float*)alloc((size_t)N * 4);
    float* stats  = (float*)alloc(512 * 4);
    float* ss     = (float*)alloc(512 * 4);
    float* gpool  = (float*)alloc(64 * H * 4);

    const int* row = ei;
    const int* col = ei + E;

    hipMemsetAsync(cnt, 0, (size_t)N * 4, stream);
    hipMemsetAsync(fill, 0, (size_t)N * 4, stream);
    zrow_kernel<<<dim3(1), 256, 0, stream>>>(hws + (size_t)N * H);

    cvt_x_kernel<<<dim3((N * IN / 4 + 255) / 256), 256, 0, stream>>>(x, xbf, N * IN);
    tr_node_kernel<<<dim3((IN * H + 255) / 256), 256, 0, stream>>>(node_w, nwT);
    tr_conv_kernel<<<dim3((L * H * H + 255) / 256), 256, 0, stream>>>(conv_w, cwT);

    deg_kernel<<<dim3((E + 255) / 256), 256, 0, stream>>>(col, cnt, E);
    dis_kernel<<<dim3((N + 255) / 256), 256, 0, stream>>>(cnt, dis, N);
    int nb = (N + 511) / 512;
    scan1_kernel<<<dim3(nb), 512, 0, stream>>>(cnt, scanbuf, bsum, N);
    scan2_kernel<<<dim3(1), 64, 0, stream>>>(bsum, boff, nb);
    scan3_kernel<<<dim3((N + 255) / 256), 256, 0, stream>>>(scanbuf, boff, rowstart, N);
    scatter_kernel<<<dim3((E + 255) / 256), 256, 0, stream>>>(row, col, rowstart, fill, eidx, E);

    dim3 gg((N + 127) / 128, H / 128);
    gemm_bt_kernel<<<gg, 256, 0, stream>>>(xbf, nwT, h, node_b, nullptr, N, IN, H);

    for (int l = 0; l < L; l++) {
        // hws = dis[v] * (h @ conv_w[l])  (scale fused into epilogue)
        gemm_bt_kernel<<<gg, 256, 0, stream>>>(h, cwT + (size_t)l * H * H, hws, nullptr, dis, N, H, H);
        hipMemsetAsync(stats, 0, 512 * 4, stream);
        agg_kernel<<<dim3((N + 15) / 16), 256, 0, stream>>>(hws, rowstart, eidx, dis,
                                                            conv_b + l * H, agg, stats, N);
        bnfin_kernel<<<dim3(1), 256, 0, stream>>>(stats, bn_g + l * H, bn_b + l * H, ss, N);
        size_t total = (size_t)N * H;
        elem_kernel<<<dim3((int)((total / 4 + 255) / 256)), 256, 0, stream>>>(agg, ss, h, total);
    }

    hipMemsetAsync(gpool, 0, 64 * H * 4, stream);
    pool_kernel<<<dim3((N + 255) / 256), 256, 0, stream>>>(h, batch, gpool, N);
    head_kernel<<<dim3(64), 128, 0, stream>>>(gpool, hw1, hb1, hw2, hb2, out);
}